// Round 3
// baseline (560.226 us; speedup 1.0000x reference)
//
#include <hip/hip_runtime.h>

typedef _Float16 f16x8 __attribute__((ext_vector_type(8)));
typedef _Float16 f16x4 __attribute__((ext_vector_type(4)));
typedef float    f32x4 __attribute__((ext_vector_type(4)));

#define MFMA16(a,b,c) __builtin_amdgcn_mfma_f32_16x16x32_f16((a),(b),(c),0,0,0)

constexpr int Bc  = 8;
constexpr int Sc  = 1024;
constexpr int Hc  = 512;
constexpr int NHc = 8;
constexpr int HDc = 64;

// ---------------------------------------------------------------------------
// Stage 0: fp32 -> fp16 convert of hs and the three W matrices (concatenated).
// ---------------------------------------------------------------------------
__global__ __launch_bounds__(256) void cvt_f16(
    const float* __restrict__ hs,
    const float* __restrict__ wq, const float* __restrict__ wk,
    const float* __restrict__ wv,
    _Float16* __restrict__ hs16, _Float16* __restrict__ w16)
{
    const size_t i4  = (size_t)blockIdx.x * 256 + threadIdx.x;  // float4 index
    const size_t HS4 = (size_t)Bc * Sc * Hc / 4;   // 1,048,576
    const size_t W4  = (size_t)Hc * Hc / 4;        // 65,536
    float4 v;
    _Float16* dst;
    if (i4 < HS4) {
        v = ((const float4*)hs)[i4];
        dst = hs16 + i4 * 4;
    } else {
        const size_t j = i4 - HS4;
        const int z = (int)(j / W4);
        const size_t o = j - (size_t)z * W4;
        const float* src = (z == 0) ? wq : (z == 1) ? wk : wv;
        v = ((const float4*)src)[o];
        dst = w16 + j * 4;
    }
    f16x4 h;
    h[0] = (_Float16)v.x; h[1] = (_Float16)v.y;
    h[2] = (_Float16)v.z; h[3] = (_Float16)v.w;
    *(f16x4*)dst = h;
}

// ---------------------------------------------------------------------------
// Stage 1: fused QKV GEMM, m97-style (unchanged).
// ---------------------------------------------------------------------------
__global__ __launch_bounds__(256) void qkv_gemm(
    const _Float16* __restrict__ A,   // [8192][512]
    const _Float16* __restrict__ Bm,  // [1536][512]
    const float* __restrict__ bq, const float* __restrict__ bk,
    const float* __restrict__ bv,
    _Float16* __restrict__ qws, _Float16* __restrict__ kws,
    _Float16* __restrict__ vws)
{
    __shared__ __align__(16) _Float16 As[128 * 64];
    __shared__ __align__(16) _Float16 Bs[128 * 64];

    const int m0 = blockIdx.x * 128;
    const int n0 = blockIdx.y * 128;
    const int tid  = threadIdx.x;
    const int lane = tid & 63;
    const int w    = tid >> 6;
    const int l15  = lane & 15;
    const int quad = lane >> 4;
    const int wm   = (w >> 1) * 64;
    const int wn   = (w & 1) * 64;

    f32x4 acc[4][4] = {};

    const int srow = tid >> 3;
    const int scol = (tid & 7) * 8;

    for (int k0 = 0; k0 < 512; k0 += 64) {
        __syncthreads();
#pragma unroll
        for (int j = 0; j < 4; ++j) {
            const _Float16* ga = A  + (size_t)(m0 + srow + 32 * j) * 512 + k0 + scol;
            const _Float16* gb = Bm + (size_t)(n0 + srow + 32 * j) * 512 + k0 + scol;
            __builtin_amdgcn_global_load_lds(
                (const __attribute__((address_space(1))) void*)ga,
                (__attribute__((address_space(3))) void*)(As + tid * 8 + j * 2048),
                16, 0, 0);
            __builtin_amdgcn_global_load_lds(
                (const __attribute__((address_space(1))) void*)gb,
                (__attribute__((address_space(3))) void*)(Bs + tid * 8 + j * 2048),
                16, 0, 0);
        }
        __syncthreads();
#pragma unroll
        for (int ks = 0; ks < 2; ++ks) {
            f16x8 af[4], bf[4];
#pragma unroll
            for (int i = 0; i < 4; ++i) {
                af[i] = *(const f16x8*)&As[(wm + i * 16 + l15) * 64 + ks * 32 + quad * 8];
                bf[i] = *(const f16x8*)&Bs[(wn + i * 16 + l15) * 64 + ks * 32 + quad * 8];
            }
#pragma unroll
            for (int mb = 0; mb < 4; ++mb)
#pragma unroll
                for (int nb = 0; nb < 4; ++nb)
                    acc[mb][nb] = MFMA16(af[mb], bf[nb], acc[mb][nb]);
        }
    }

    const int zsel = n0 >> 9;
    const float* bias = (zsel == 0) ? bq : (zsel == 1) ? bk : bv;
#pragma unroll
    for (int nb = 0; nb < 4; ++nb) {
        const int n  = n0 + wn + nb * 16 + l15;
        const int nn = n & 511;
        const int h  = nn >> 6;
        const int hd = nn & 63;
        const float bvv = bias[nn];
#pragma unroll
        for (int mb = 0; mb < 4; ++mb) {
            const int m = m0 + wm + mb * 16 + quad * 4;
            const int b = m >> 10;
            const int s = m & 1023;
            if (zsel == 2) {
                f16x4 t;
#pragma unroll
                for (int rr = 0; rr < 4; ++rr)
                    t[rr] = (_Float16)(acc[mb][nb][rr] + bvv);
                *(f16x4*)&vws[((size_t)(b * NHc + h) * HDc + hd) * Sc + s] = t;
            } else {
                _Float16* dst = (zsel == 0 ? qws : kws)
                              + ((size_t)(b * NHc + h) * Sc + s) * HDc + hd;
#pragma unroll
                for (int rr = 0; rr < 4; ++rr)
                    dst[(size_t)rr * HDc] = (_Float16)(acc[mb][nb][rr] + bvv);
            }
        }
    }
}

// ---------------------------------------------------------------------------
// Stage 2: flash attention. v7: per-wave vectorized rel prefetch.
//
// v6 post-mortem: the producer/LDS-DMA ring died because LLVM's waitcnt pass
// drains vmcnt(0) at s_barrier whenever global_load_lds is pending -> one
// tile of flight, same 1.3 TB/s plateau as v4/v5 (measured in-flight/CU ~2KB).
//
// v7: no barriers, no LDS-DMA, no producer (back to 2 waves / 128 threads).
// Each wave prefetches ITS OWN next rel tile (16 rows x 64 cols fp32) as
// 4 x float4 (1KB/instr, per-row-64B-coalesced), parks it in VGPRs across the
// whole tile compute, then ds_writes to a PRIVATE per-wave LDS buffer
// ([16][68] pad: float4 write uniform 8/bank = conflict-free; scalar C-layout
// readback 2-way = free). vmcnt order is respected by construction:
//   loop top: wait rel(kt) [vmcnt(0), only rel outstanding] -> ds_write
//   issue mask,K(kt) -> QK waits K (drains nothing else)
//   issue V(kt) -> issue rel(kt+1)
//   softmax reads rel(kt) from LDS (lgkm, independent of vmcnt)
//   PV waits V = vmcnt(4) -> rel(kt+1) SURVIVES, flight ~ full tile period.
// In-flight rel: 16 waves/CU x 4KB = 64KB >> ~22KB needed for 6.3 TB/s.
// sched_barrier(0) fences pin the issue regions.
// ---------------------------------------------------------------------------
__global__ __launch_bounds__(128, 4) void attn(
    const _Float16* __restrict__ qws, const _Float16* __restrict__ kws,
    const _Float16* __restrict__ vws, const float* __restrict__ rel,
    const float* __restrict__ mask, float* __restrict__ out)
{
    const int qt = blockIdx.x;      // 0..31 (32 q-rows per block)
    const int bh = blockIdx.y;      // 0..63
    const int b  = bh >> 3;
    const int h  = bh & 7;
    const int tid  = threadIdx.x;
    const int w    = tid >> 6;      // 0..1
    const int lane = tid & 63;
    const int l15  = lane & 15;
    const int quad = lane >> 4;
    const int q0w  = qt * 32 + w * 16;

    __shared__ __align__(16) float    rel_lds[2][16][68];  // per-wave, padded
    __shared__ __align__(16) _Float16 lds_p[2][16][72];    // per-wave slice

    const _Float16* qh = qws + (size_t)bh * Sc * HDc;
    const _Float16* kh = kws + (size_t)bh * Sc * HDc;
    const _Float16* vh = vws + (size_t)bh * HDc * Sc;
    const float* relh  = rel + (size_t)bh * Sc * Sc;
    const float* maskb = mask + (size_t)b * Sc;

    // rel prefetch mapping: lane -> row=l15, col = quad*4 + g*16 (g=0..3).
    // Per row, lanes {r, r+16, r+32, r+48} cover 16 consecutive floats (64B).
    const float* relp = relh + (size_t)(q0w + l15) * Sc + quad * 4;

    float4 rl[4];
#pragma unroll
    for (int g = 0; g < 4; ++g)
        rl[g] = *(const float4*)(relp + g * 16);

    f16x8 qf0 = *(const f16x8*)(qh + (size_t)(q0w + l15) * HDc + quad * 8);
    f16x8 qf1 = *(const f16x8*)(qh + (size_t)(q0w + l15) * HDc + 32 + quad * 8);

    float m_run[4], l_run[4];
    f32x4 o[4] = {};
#pragma unroll
    for (int rj = 0; rj < 4; ++rj) { m_run[rj] = -1e30f; l_run[rj] = 0.f; }

#pragma unroll 1
    for (int kt = 0; kt < 16; ++kt) {
        const int kbase = kt * 64;

        // ---- (1) park rel(kt) into private LDS (waits only rel's vmcnt) ---
#pragma unroll
        for (int g = 0; g < 4; ++g)
            *(float4*)&rel_lds[w][l15][quad * 4 + g * 16] = rl[g];
        __builtin_amdgcn_sched_barrier(0);

        // ---- (2) issue mask + K ------------------------------------------
        float mk[4];
#pragma unroll
        for (int nb = 0; nb < 4; ++nb)
            mk[nb] = maskb[kbase + nb * 16 + l15];
        f16x8 kf0[4], kf1[4];
#pragma unroll
        for (int nb = 0; nb < 4; ++nb) {
            const _Float16* kp = kh + (size_t)(kbase + nb * 16 + l15) * HDc + quad * 8;
            kf0[nb] = *(const f16x8*)kp;
            kf1[nb] = *(const f16x8*)(kp + 32);
        }
        __builtin_amdgcn_sched_barrier(0);

        // ---- (3) S = Q K^T (wait on K drains nothing precious) ------------
        f32x4 sc[4] = {};
#pragma unroll
        for (int nb = 0; nb < 4; ++nb) {
            sc[nb] = MFMA16(qf0, kf0[nb], sc[nb]);
            sc[nb] = MFMA16(qf1, kf1[nb], sc[nb]);
        }
        __builtin_amdgcn_sched_barrier(0);

        // ---- (4) issue V --------------------------------------------------
        f16x8 vf0[4], vf1[4];
#pragma unroll
        for (int nb = 0; nb < 4; ++nb) {
            const _Float16* vp = vh + (size_t)(nb * 16 + l15) * Sc + kbase + quad * 8;
            vf0[nb] = *(const f16x8*)vp;
            vf1[nb] = *(const f16x8*)(vp + 32);
        }

        // ---- (5) issue rel(kt+1): AFTER V so PV's vmcnt(4) keeps it -------
        if (kt < 15) {
#pragma unroll
            for (int g = 0; g < 4; ++g)
                rl[g] = *(const float4*)(relp + kbase + 64 + g * 16);
        }
        __builtin_amdgcn_sched_barrier(0);

        // ---- (6) scale + rel (from LDS, lgkm) + mask; online softmax ------
        float rb[16];
#pragma unroll
        for (int nb = 0; nb < 4; ++nb)
#pragma unroll
            for (int rj = 0; rj < 4; ++rj)
                rb[nb * 4 + rj] = rel_lds[w][quad * 4 + rj][nb * 16 + l15];

#pragma unroll
        for (int nb = 0; nb < 4; ++nb)
#pragma unroll
            for (int rj = 0; rj < 4; ++rj)
                sc[nb][rj] = sc[nb][rj] * 0.125f + rb[nb * 4 + rj] + mk[nb];

#pragma unroll
        for (int rj = 0; rj < 4; ++rj) {
            float mx = fmaxf(fmaxf(sc[0][rj], sc[1][rj]), fmaxf(sc[2][rj], sc[3][rj]));
#pragma unroll
            for (int off = 1; off < 16; off <<= 1) mx = fmaxf(mx, __shfl_xor(mx, off));
            const float mnew  = fmaxf(m_run[rj], mx);
            const float alpha = __expf(m_run[rj] - mnew);
            float rs = 0.f;
#pragma unroll
            for (int nb = 0; nb < 4; ++nb) {
                const float p = __expf(sc[nb][rj] - mnew);
                sc[nb][rj] = p;
                rs += p;
            }
#pragma unroll
            for (int off = 1; off < 16; off <<= 1) rs += __shfl_xor(rs, off);
            m_run[rj] = mnew;
            l_run[rj] = l_run[rj] * alpha + rs;
            o[0][rj] *= alpha; o[1][rj] *= alpha; o[2][rj] *= alpha; o[3][rj] *= alpha;
        }

        // ---- (7) P: C layout -> A layout via per-wave LDS (no barriers) ---
#pragma unroll
        for (int nb = 0; nb < 4; ++nb)
#pragma unroll
            for (int rj = 0; rj < 4; ++rj)
                lds_p[w][quad * 4 + rj][nb * 16 + l15] = (_Float16)sc[nb][rj];
        f16x8 ap0 = *(const f16x8*)&lds_p[w][l15][quad * 8];
        f16x8 ap1 = *(const f16x8*)&lds_p[w][l15][32 + quad * 8];

        // ---- (8) O += P V (wait V = vmcnt(4): rel(kt+1) stays in flight) --
#pragma unroll
        for (int nb = 0; nb < 4; ++nb) {
            o[nb] = MFMA16(ap0, vf0[nb], o[nb]);
            o[nb] = MFMA16(ap1, vf1[nb], o[nb]);
        }
    }

    // ---- epilogue ---------------------------------------------------------
#pragma unroll
    for (int rj = 0; rj < 4; ++rj) {
        const float linv = 1.0f / l_run[rj];
        const int qrow = q0w + quad * 4 + rj;
#pragma unroll
        for (int nb = 0; nb < 4; ++nb)
            out[((size_t)(b * Sc + qrow)) * Hc + h * HDc + nb * 16 + l15] =
                o[nb][rj] * linv;
    }
}

extern "C" void kernel_launch(void* const* d_in, const int* in_sizes, int n_in,
                              void* d_out, int out_size, void* d_ws, size_t ws_size,
                              hipStream_t stream) {
    const float* hs   = (const float*)d_in[0];
    const float* mask = (const float*)d_in[1];
    const float* rel  = (const float*)d_in[2];
    const float* Wq   = (const float*)d_in[3];
    const float* bq   = (const float*)d_in[4];
    const float* Wk   = (const float*)d_in[5];
    const float* bk   = (const float*)d_in[6];
    const float* Wv   = (const float*)d_in[7];
    const float* bv   = (const float*)d_in[8];
    float* out = (float*)d_out;

    const size_t elems = (size_t)Bc * Sc * Hc;        // 4,194,304
    _Float16* hs16 = (_Float16*)d_ws;                 // 8 MB
    _Float16* w16  = hs16 + elems;                    // 1.5 MB
    _Float16* qws  = w16 + (size_t)3 * Hc * Hc;       // 8 MB
    _Float16* kws  = qws + elems;                     // 8 MB
    _Float16* vws  = kws + elems;                     // 8 MB   (total ~33.5 MB)

    const int cvt_blocks = (int)(((size_t)Bc * Sc * Hc + 3 * Hc * Hc) / 4 / 256);
    cvt_f16<<<cvt_blocks, 256, 0, stream>>>(hs, Wq, Wk, Wv, hs16, w16);
    qkv_gemm<<<dim3(64, 12), 256, 0, stream>>>(hs16, w16, bq, bk, bv,
                                               qws, kws, vws);
    attn<<<dim3(32, 64), 128, 0, stream>>>(qws, kws, vws, rel, mask, out);
}

// Round 4
// 559.210 us; speedup vs baseline: 1.0018x; 1.0018x over previous
//
#include <hip/hip_runtime.h>

typedef _Float16 f16x8 __attribute__((ext_vector_type(8)));
typedef _Float16 f16x4 __attribute__((ext_vector_type(4)));
typedef float    f32x4 __attribute__((ext_vector_type(4)));

#define MFMA16(a,b,c) __builtin_amdgcn_mfma_f32_16x16x32_f16((a),(b),(c),0,0,0)

constexpr int Bc  = 8;
constexpr int Sc  = 1024;
constexpr int Hc  = 512;
constexpr int NHc = 8;
constexpr int HDc = 64;

// ---------------------------------------------------------------------------
// Stage 0: fp32 -> fp16 convert of hs and the three W matrices (concatenated).
// ---------------------------------------------------------------------------
__global__ __launch_bounds__(256) void cvt_f16(
    const float* __restrict__ hs,
    const float* __restrict__ wq, const float* __restrict__ wk,
    const float* __restrict__ wv,
    _Float16* __restrict__ hs16, _Float16* __restrict__ w16)
{
    const size_t i4  = (size_t)blockIdx.x * 256 + threadIdx.x;  // float4 index
    const size_t HS4 = (size_t)Bc * Sc * Hc / 4;   // 1,048,576
    const size_t W4  = (size_t)Hc * Hc / 4;        // 65,536
    float4 v;
    _Float16* dst;
    if (i4 < HS4) {
        v = ((const float4*)hs)[i4];
        dst = hs16 + i4 * 4;
    } else {
        const size_t j = i4 - HS4;
        const int z = (int)(j / W4);
        const size_t o = j - (size_t)z * W4;
        const float* src = (z == 0) ? wq : (z == 1) ? wk : wv;
        v = ((const float4*)src)[o];
        dst = w16 + j * 4;
    }
    f16x4 h;
    h[0] = (_Float16)v.x; h[1] = (_Float16)v.y;
    h[2] = (_Float16)v.z; h[3] = (_Float16)v.w;
    *(f16x4*)dst = h;
}

// ---------------------------------------------------------------------------
// Stage 1: fused QKV GEMM, m97-style (unchanged).
// ---------------------------------------------------------------------------
__global__ __launch_bounds__(256) void qkv_gemm(
    const _Float16* __restrict__ A,   // [8192][512]
    const _Float16* __restrict__ Bm,  // [1536][512]
    const float* __restrict__ bq, const float* __restrict__ bk,
    const float* __restrict__ bv,
    _Float16* __restrict__ qws, _Float16* __restrict__ kws,
    _Float16* __restrict__ vws)
{
    __shared__ __align__(16) _Float16 As[128 * 64];
    __shared__ __align__(16) _Float16 Bs[128 * 64];

    const int m0 = blockIdx.x * 128;
    const int n0 = blockIdx.y * 128;
    const int tid  = threadIdx.x;
    const int lane = tid & 63;
    const int w    = tid >> 6;
    const int l15  = lane & 15;
    const int quad = lane >> 4;
    const int wm   = (w >> 1) * 64;
    const int wn   = (w & 1) * 64;

    f32x4 acc[4][4] = {};

    const int srow = tid >> 3;
    const int scol = (tid & 7) * 8;

    for (int k0 = 0; k0 < 512; k0 += 64) {
        __syncthreads();
#pragma unroll
        for (int j = 0; j < 4; ++j) {
            const _Float16* ga = A  + (size_t)(m0 + srow + 32 * j) * 512 + k0 + scol;
            const _Float16* gb = Bm + (size_t)(n0 + srow + 32 * j) * 512 + k0 + scol;
            __builtin_amdgcn_global_load_lds(
                (const __attribute__((address_space(1))) void*)ga,
                (__attribute__((address_space(3))) void*)(As + tid * 8 + j * 2048),
                16, 0, 0);
            __builtin_amdgcn_global_load_lds(
                (const __attribute__((address_space(1))) void*)gb,
                (__attribute__((address_space(3))) void*)(Bs + tid * 8 + j * 2048),
                16, 0, 0);
        }
        __syncthreads();
#pragma unroll
        for (int ks = 0; ks < 2; ++ks) {
            f16x8 af[4], bf[4];
#pragma unroll
            for (int i = 0; i < 4; ++i) {
                af[i] = *(const f16x8*)&As[(wm + i * 16 + l15) * 64 + ks * 32 + quad * 8];
                bf[i] = *(const f16x8*)&Bs[(wn + i * 16 + l15) * 64 + ks * 32 + quad * 8];
            }
#pragma unroll
            for (int mb = 0; mb < 4; ++mb)
#pragma unroll
                for (int nb = 0; nb < 4; ++nb)
                    acc[mb][nb] = MFMA16(af[mb], bf[nb], acc[mb][nb]);
        }
    }

    const int zsel = n0 >> 9;
    const float* bias = (zsel == 0) ? bq : (zsel == 1) ? bk : bv;
#pragma unroll
    for (int nb = 0; nb < 4; ++nb) {
        const int n  = n0 + wn + nb * 16 + l15;
        const int nn = n & 511;
        const int h  = nn >> 6;
        const int hd = nn & 63;
        const float bvv = bias[nn];
#pragma unroll
        for (int mb = 0; mb < 4; ++mb) {
            const int m = m0 + wm + mb * 16 + quad * 4;
            const int b = m >> 10;
            const int s = m & 1023;
            if (zsel == 2) {
                f16x4 t;
#pragma unroll
                for (int rr = 0; rr < 4; ++rr)
                    t[rr] = (_Float16)(acc[mb][nb][rr] + bvv);
                *(f16x4*)&vws[((size_t)(b * NHc + h) * HDc + hd) * Sc + s] = t;
            } else {
                _Float16* dst = (zsel == 0 ? qws : kws)
                              + ((size_t)(b * NHc + h) * Sc + s) * HDc + hd;
#pragma unroll
                for (int rr = 0; rr < 4; ++rr)
                    dst[(size_t)rr * HDc] = (_Float16)(acc[mb][nb][rr] + bvv);
            }
        }
    }
}

// ---------------------------------------------------------------------------
// Stage 2: flash attention. v8 = v7 structure + two fixes.
//
// v7 post-mortem: (a) __launch_bounds__(128,4) capped VGPR at 128 < the ~146
// the structure needs -> compiler spilled rl[] to scratch every iter
// (WRITE_SIZE 16->252 MB, VGPR=60). Fixed: (128,3) -> 170-VGPR budget.
// (b) The deeper finding: v4/v5/v6 ALL plateau at 1.24-1.4 TB/s on rel, even
// v6 whose LDS-DMA producer provably had ~48KB/CU in flight. The limiter is
// the ADDRESS PATTERN, not MLP: every block reads the same 256B column
// stripe (cols kt*64..) of 4KB rel rows in near-lockstep -> with <=4KB
// channel interleave, a GPU-wide synchronized 256B-stripe-at-4KB-stride
// stream activates only a fraction of HBM channels.
//
// v8 fix: DEPHASE the k-loop. Online softmax is k-order-invariant, so block
// (qt,bh) starts at tile phase=(qt+bh)&15 and walks tiles mod 16. Resident
// blocks then cover all 16 column stripes simultaneously -> uniform channel
// load, no extra traffic, no precision change.
// ---------------------------------------------------------------------------
__global__ __launch_bounds__(128, 3) void attn(
    const _Float16* __restrict__ qws, const _Float16* __restrict__ kws,
    const _Float16* __restrict__ vws, const float* __restrict__ rel,
    const float* __restrict__ mask, float* __restrict__ out)
{
    const int qt = blockIdx.x;      // 0..31 (32 q-rows per block)
    const int bh = blockIdx.y;      // 0..63
    const int b  = bh >> 3;
    const int h  = bh & 7;
    const int tid  = threadIdx.x;
    const int w    = tid >> 6;      // 0..1
    const int lane = tid & 63;
    const int l15  = lane & 15;
    const int quad = lane >> 4;
    const int q0w  = qt * 32 + w * 16;
    const int phase = (qt + bh) & 15;

    __shared__ __align__(16) float    rel_lds[2][16][68];  // per-wave, padded
    __shared__ __align__(16) _Float16 lds_p[2][16][72];    // per-wave slice

    const _Float16* qh = qws + (size_t)bh * Sc * HDc;
    const _Float16* kh = kws + (size_t)bh * Sc * HDc;
    const _Float16* vh = vws + (size_t)bh * HDc * Sc;
    const float* relh  = rel + (size_t)bh * Sc * Sc;
    const float* maskb = mask + (size_t)b * Sc;

    // rel prefetch mapping: lane -> row=l15, col = quad*4 + g*16 (g=0..3).
    // Per row, lanes {r, r+16, r+32, r+48} cover 16 consecutive floats (64B).
    const float* relp = relh + (size_t)(q0w + l15) * Sc + quad * 4;

    float4 rl[4];
#pragma unroll
    for (int g = 0; g < 4; ++g)
        rl[g] = *(const float4*)(relp + phase * 64 + g * 16);

    f16x8 qf0 = *(const f16x8*)(qh + (size_t)(q0w + l15) * HDc + quad * 8);
    f16x8 qf1 = *(const f16x8*)(qh + (size_t)(q0w + l15) * HDc + 32 + quad * 8);

    float m_run[4], l_run[4];
    f32x4 o[4] = {};
#pragma unroll
    for (int rj = 0; rj < 4; ++rj) { m_run[rj] = -1e30f; l_run[rj] = 0.f; }

#pragma unroll 1
    for (int i = 0; i < 16; ++i) {
        const int kt    = (phase + i) & 15;
        const int kbase = kt * 64;

        // ---- (1) park rel(tile i) into private LDS (waits only rel vmcnt) -
#pragma unroll
        for (int g = 0; g < 4; ++g)
            *(float4*)&rel_lds[w][l15][quad * 4 + g * 16] = rl[g];
        __builtin_amdgcn_sched_barrier(0);

        // ---- (2) issue mask + K ------------------------------------------
        float mk[4];
#pragma unroll
        for (int nb = 0; nb < 4; ++nb)
            mk[nb] = maskb[kbase + nb * 16 + l15];
        f16x8 kf0[4], kf1[4];
#pragma unroll
        for (int nb = 0; nb < 4; ++nb) {
            const _Float16* kp = kh + (size_t)(kbase + nb * 16 + l15) * HDc + quad * 8;
            kf0[nb] = *(const f16x8*)kp;
            kf1[nb] = *(const f16x8*)(kp + 32);
        }
        __builtin_amdgcn_sched_barrier(0);

        // ---- (3) S = Q K^T (wait on K drains nothing precious) ------------
        f32x4 sc[4] = {};
#pragma unroll
        for (int nb = 0; nb < 4; ++nb) {
            sc[nb] = MFMA16(qf0, kf0[nb], sc[nb]);
            sc[nb] = MFMA16(qf1, kf1[nb], sc[nb]);
        }
        __builtin_amdgcn_sched_barrier(0);

        // ---- (4) issue V --------------------------------------------------
        f16x8 vf0[4], vf1[4];
#pragma unroll
        for (int nb = 0; nb < 4; ++nb) {
            const _Float16* vp = vh + (size_t)(nb * 16 + l15) * Sc + kbase + quad * 8;
            vf0[nb] = *(const f16x8*)vp;
            vf1[nb] = *(const f16x8*)(vp + 32);
        }

        // ---- (5) issue rel(tile i+1): AFTER V so PV's wait keeps it -------
        if (i < 15) {
            const int knext = ((phase + i + 1) & 15) * 64;
#pragma unroll
            for (int g = 0; g < 4; ++g)
                rl[g] = *(const float4*)(relp + knext + g * 16);
        }
        __builtin_amdgcn_sched_barrier(0);

        // ---- (6) scale + rel (from LDS, lgkm) + mask; online softmax ------
        float rb[16];
#pragma unroll
        for (int nb = 0; nb < 4; ++nb)
#pragma unroll
            for (int rj = 0; rj < 4; ++rj)
                rb[nb * 4 + rj] = rel_lds[w][quad * 4 + rj][nb * 16 + l15];

#pragma unroll
        for (int nb = 0; nb < 4; ++nb)
#pragma unroll
            for (int rj = 0; rj < 4; ++rj)
                sc[nb][rj] = sc[nb][rj] * 0.125f + rb[nb * 4 + rj] + mk[nb];

#pragma unroll
        for (int rj = 0; rj < 4; ++rj) {
            float mx = fmaxf(fmaxf(sc[0][rj], sc[1][rj]), fmaxf(sc[2][rj], sc[3][rj]));
#pragma unroll
            for (int off = 1; off < 16; off <<= 1) mx = fmaxf(mx, __shfl_xor(mx, off));
            const float mnew  = fmaxf(m_run[rj], mx);
            const float alpha = __expf(m_run[rj] - mnew);
            float rs = 0.f;
#pragma unroll
            for (int nb = 0; nb < 4; ++nb) {
                const float p = __expf(sc[nb][rj] - mnew);
                sc[nb][rj] = p;
                rs += p;
            }
#pragma unroll
            for (int off = 1; off < 16; off <<= 1) rs += __shfl_xor(rs, off);
            m_run[rj] = mnew;
            l_run[rj] = l_run[rj] * alpha + rs;
            o[0][rj] *= alpha; o[1][rj] *= alpha; o[2][rj] *= alpha; o[3][rj] *= alpha;
        }

        // ---- (7) P: C layout -> A layout via per-wave LDS (no barriers) ---
#pragma unroll
        for (int nb = 0; nb < 4; ++nb)
#pragma unroll
            for (int rj = 0; rj < 4; ++rj)
                lds_p[w][quad * 4 + rj][nb * 16 + l15] = (_Float16)sc[nb][rj];
        f16x8 ap0 = *(const f16x8*)&lds_p[w][l15][quad * 8];
        f16x8 ap1 = *(const f16x8*)&lds_p[w][l15][32 + quad * 8];

        // ---- (8) O += P V (wait V: rel(tile i+1) stays in flight) ---------
#pragma unroll
        for (int nb = 0; nb < 4; ++nb) {
            o[nb] = MFMA16(ap0, vf0[nb], o[nb]);
            o[nb] = MFMA16(ap1, vf1[nb], o[nb]);
        }
    }

    // ---- epilogue ---------------------------------------------------------
#pragma unroll
    for (int rj = 0; rj < 4; ++rj) {
        const float linv = 1.0f / l_run[rj];
        const int qrow = q0w + quad * 4 + rj;
#pragma unroll
        for (int nb = 0; nb < 4; ++nb)
            out[((size_t)(b * Sc + qrow)) * Hc + h * HDc + nb * 16 + l15] =
                o[nb][rj] * linv;
    }
}

extern "C" void kernel_launch(void* const* d_in, const int* in_sizes, int n_in,
                              void* d_out, int out_size, void* d_ws, size_t ws_size,
                              hipStream_t stream) {
    const float* hs   = (const float*)d_in[0];
    const float* mask = (const float*)d_in[1];
    const float* rel  = (const float*)d_in[2];
    const float* Wq   = (const float*)d_in[3];
    const float* bq   = (const float*)d_in[4];
    const float* Wk   = (const float*)d_in[5];
    const float* bk   = (const float*)d_in[6];
    const float* Wv   = (const float*)d_in[7];
    const float* bv   = (const float*)d_in[8];
    float* out = (float*)d_out;

    const size_t elems = (size_t)Bc * Sc * Hc;        // 4,194,304
    _Float16* hs16 = (_Float16*)d_ws;                 // 8 MB
    _Float16* w16  = hs16 + elems;                    // 1.5 MB
    _Float16* qws  = w16 + (size_t)3 * Hc * Hc;       // 8 MB
    _Float16* kws  = qws + elems;                     // 8 MB
    _Float16* vws  = kws + elems;                     // 8 MB   (total ~33.5 MB)

    const int cvt_blocks = (int)(((size_t)Bc * Sc * Hc + 3 * Hc * Hc) / 4 / 256);
    cvt_f16<<<cvt_blocks, 256, 0, stream>>>(hs, Wq, Wk, Wv, hs16, w16);
    qkv_gemm<<<dim3(64, 12), 256, 0, stream>>>(hs16, w16, bq, bk, bv,
                                               qws, kws, vws);
    attn<<<dim3(32, 64), 128, 0, stream>>>(qws, kws, vws, rel, mask, out);
}

// Round 5
// 504.323 us; speedup vs baseline: 1.1108x; 1.1088x over previous
//
#include <hip/hip_runtime.h>

typedef _Float16 f16x8 __attribute__((ext_vector_type(8)));
typedef _Float16 f16x4 __attribute__((ext_vector_type(4)));
typedef float    f32x4 __attribute__((ext_vector_type(4)));

#define MFMA16(a,b,c) __builtin_amdgcn_mfma_f32_16x16x32_f16((a),(b),(c),0,0,0)

constexpr int Bc  = 8;
constexpr int Sc  = 1024;
constexpr int Hc  = 512;
constexpr int NHc = 8;
constexpr int HDc = 64;

// ---------------------------------------------------------------------------
// Stage 0: fp32 -> fp16 convert of hs and the three W matrices (concatenated).
// ---------------------------------------------------------------------------
__global__ __launch_bounds__(256) void cvt_f16(
    const float* __restrict__ hs,
    const float* __restrict__ wq, const float* __restrict__ wk,
    const float* __restrict__ wv,
    _Float16* __restrict__ hs16, _Float16* __restrict__ w16)
{
    const size_t i4  = (size_t)blockIdx.x * 256 + threadIdx.x;  // float4 index
    const size_t HS4 = (size_t)Bc * Sc * Hc / 4;   // 1,048,576
    const size_t W4  = (size_t)Hc * Hc / 4;        // 65,536
    float4 v;
    _Float16* dst;
    if (i4 < HS4) {
        v = ((const float4*)hs)[i4];
        dst = hs16 + i4 * 4;
    } else {
        const size_t j = i4 - HS4;
        const int z = (int)(j / W4);
        const size_t o = j - (size_t)z * W4;
        const float* src = (z == 0) ? wq : (z == 1) ? wk : wv;
        v = ((const float4*)src)[o];
        dst = w16 + j * 4;
    }
    f16x4 h;
    h[0] = (_Float16)v.x; h[1] = (_Float16)v.y;
    h[2] = (_Float16)v.z; h[3] = (_Float16)v.w;
    *(f16x4*)dst = h;
}

// ---------------------------------------------------------------------------
// Stage 1: fused QKV GEMM, m97-style (unchanged).
// ---------------------------------------------------------------------------
__global__ __launch_bounds__(256) void qkv_gemm(
    const _Float16* __restrict__ A,   // [8192][512]
    const _Float16* __restrict__ Bm,  // [1536][512]
    const float* __restrict__ bq, const float* __restrict__ bk,
    const float* __restrict__ bv,
    _Float16* __restrict__ qws, _Float16* __restrict__ kws,
    _Float16* __restrict__ vws)
{
    __shared__ __align__(16) _Float16 As[128 * 64];
    __shared__ __align__(16) _Float16 Bs[128 * 64];

    const int m0 = blockIdx.x * 128;
    const int n0 = blockIdx.y * 128;
    const int tid  = threadIdx.x;
    const int lane = tid & 63;
    const int w    = tid >> 6;
    const int l15  = lane & 15;
    const int quad = lane >> 4;
    const int wm   = (w >> 1) * 64;
    const int wn   = (w & 1) * 64;

    f32x4 acc[4][4] = {};

    const int srow = tid >> 3;
    const int scol = (tid & 7) * 8;

    for (int k0 = 0; k0 < 512; k0 += 64) {
        __syncthreads();
#pragma unroll
        for (int j = 0; j < 4; ++j) {
            const _Float16* ga = A  + (size_t)(m0 + srow + 32 * j) * 512 + k0 + scol;
            const _Float16* gb = Bm + (size_t)(n0 + srow + 32 * j) * 512 + k0 + scol;
            __builtin_amdgcn_global_load_lds(
                (const __attribute__((address_space(1))) void*)ga,
                (__attribute__((address_space(3))) void*)(As + tid * 8 + j * 2048),
                16, 0, 0);
            __builtin_amdgcn_global_load_lds(
                (const __attribute__((address_space(1))) void*)gb,
                (__attribute__((address_space(3))) void*)(Bs + tid * 8 + j * 2048),
                16, 0, 0);
        }
        __syncthreads();
#pragma unroll
        for (int ks = 0; ks < 2; ++ks) {
            f16x8 af[4], bf[4];
#pragma unroll
            for (int i = 0; i < 4; ++i) {
                af[i] = *(const f16x8*)&As[(wm + i * 16 + l15) * 64 + ks * 32 + quad * 8];
                bf[i] = *(const f16x8*)&Bs[(wn + i * 16 + l15) * 64 + ks * 32 + quad * 8];
            }
#pragma unroll
            for (int mb = 0; mb < 4; ++mb)
#pragma unroll
                for (int nb = 0; nb < 4; ++nb)
                    acc[mb][nb] = MFMA16(af[mb], bf[nb], acc[mb][nb]);
        }
    }

    const int zsel = n0 >> 9;
    const float* bias = (zsel == 0) ? bq : (zsel == 1) ? bk : bv;
#pragma unroll
    for (int nb = 0; nb < 4; ++nb) {
        const int n  = n0 + wn + nb * 16 + l15;
        const int nn = n & 511;
        const int h  = nn >> 6;
        const int hd = nn & 63;
        const float bvv = bias[nn];
#pragma unroll
        for (int mb = 0; mb < 4; ++mb) {
            const int m = m0 + wm + mb * 16 + quad * 4;
            const int b = m >> 10;
            const int s = m & 1023;
            if (zsel == 2) {
                f16x4 t;
#pragma unroll
                for (int rr = 0; rr < 4; ++rr)
                    t[rr] = (_Float16)(acc[mb][nb][rr] + bvv);
                *(f16x4*)&vws[((size_t)(b * NHc + h) * HDc + hd) * Sc + s] = t;
            } else {
                _Float16* dst = (zsel == 0 ? qws : kws)
                              + ((size_t)(b * NHc + h) * Sc + s) * HDc + hd;
#pragma unroll
                for (int rr = 0; rr < 4; ++rr)
                    dst[(size_t)rr * HDc] = (_Float16)(acc[mb][nb][rr] + bvv);
            }
        }
    }
}

// ---------------------------------------------------------------------------
// Stage 2: flash attention. v9 = v8 structure + forced register budget.
//
// v8 post-mortem: dephasing worked (+32% achieved BW) but VGPR stayed 60 and
// WRITE_SIZE stayed 262MB: __launch_bounds__'s 2nd arg only sets the MIN
// waves/EU (a budget permission). The AMDGPU scheduler still TARGETS max
// occupancy (8 waves/EU = 64-VGPR budget) and spills rl[] to scratch to get
// there. The spill store needs the loaded value -> forces a vmcnt wait right
// after issue -> rel flight ~ 0 -> latency-serialized (why +32% BW gave 0 us).
//
// v9 fix: __attribute__((amdgpu_waves_per_eu(2,3))): min 2 -> 256-VGPR
// budget; MAX 3 -> the scheduler stops squeezing registers to chase 8
// waves/EU, so it has no reason to spill the parked rel tile. Everything
// else (v8 per-wave float4 rel prefetch + private-LDS park + k-loop
// dephasing) unchanged.
// ---------------------------------------------------------------------------
__global__ __launch_bounds__(128)
__attribute__((amdgpu_waves_per_eu(2, 3)))
void attn(
    const _Float16* __restrict__ qws, const _Float16* __restrict__ kws,
    const _Float16* __restrict__ vws, const float* __restrict__ rel,
    const float* __restrict__ mask, float* __restrict__ out)
{
    const int qt = blockIdx.x;      // 0..31 (32 q-rows per block)
    const int bh = blockIdx.y;      // 0..63
    const int b  = bh >> 3;
    const int h  = bh & 7;
    const int tid  = threadIdx.x;
    const int w    = tid >> 6;      // 0..1
    const int lane = tid & 63;
    const int l15  = lane & 15;
    const int quad = lane >> 4;
    const int q0w  = qt * 32 + w * 16;
    const int phase = (qt + bh) & 15;

    __shared__ __align__(16) float    rel_lds[2][16][68];  // per-wave, padded
    __shared__ __align__(16) _Float16 lds_p[2][16][72];    // per-wave slice

    const _Float16* qh = qws + (size_t)bh * Sc * HDc;
    const _Float16* kh = kws + (size_t)bh * Sc * HDc;
    const _Float16* vh = vws + (size_t)bh * HDc * Sc;
    const float* relh  = rel + (size_t)bh * Sc * Sc;
    const float* maskb = mask + (size_t)b * Sc;

    // rel prefetch mapping: lane -> row=l15, col = quad*4 + g*16 (g=0..3).
    // Per row, lanes {r, r+16, r+32, r+48} cover 16 consecutive floats (64B).
    const float* relp = relh + (size_t)(q0w + l15) * Sc + quad * 4;

    float4 rl[4];
#pragma unroll
    for (int g = 0; g < 4; ++g)
        rl[g] = *(const float4*)(relp + phase * 64 + g * 16);

    f16x8 qf0 = *(const f16x8*)(qh + (size_t)(q0w + l15) * HDc + quad * 8);
    f16x8 qf1 = *(const f16x8*)(qh + (size_t)(q0w + l15) * HDc + 32 + quad * 8);

    float m_run[4], l_run[4];
    f32x4 o[4] = {};
#pragma unroll
    for (int rj = 0; rj < 4; ++rj) { m_run[rj] = -1e30f; l_run[rj] = 0.f; }

#pragma unroll 1
    for (int i = 0; i < 16; ++i) {
        const int kt    = (phase + i) & 15;
        const int kbase = kt * 64;

        // ---- (1) park rel(tile i) into private LDS (waits only rel vmcnt) -
#pragma unroll
        for (int g = 0; g < 4; ++g)
            *(float4*)&rel_lds[w][l15][quad * 4 + g * 16] = rl[g];
        __builtin_amdgcn_sched_barrier(0);

        // ---- (2) issue mask + K ------------------------------------------
        float mk[4];
#pragma unroll
        for (int nb = 0; nb < 4; ++nb)
            mk[nb] = maskb[kbase + nb * 16 + l15];
        f16x8 kf0[4], kf1[4];
#pragma unroll
        for (int nb = 0; nb < 4; ++nb) {
            const _Float16* kp = kh + (size_t)(kbase + nb * 16 + l15) * HDc + quad * 8;
            kf0[nb] = *(const f16x8*)kp;
            kf1[nb] = *(const f16x8*)(kp + 32);
        }
        __builtin_amdgcn_sched_barrier(0);

        // ---- (3) S = Q K^T (wait on K drains nothing precious) ------------
        f32x4 sc[4] = {};
#pragma unroll
        for (int nb = 0; nb < 4; ++nb) {
            sc[nb] = MFMA16(qf0, kf0[nb], sc[nb]);
            sc[nb] = MFMA16(qf1, kf1[nb], sc[nb]);
        }
        __builtin_amdgcn_sched_barrier(0);

        // ---- (4) issue V --------------------------------------------------
        f16x8 vf0[4], vf1[4];
#pragma unroll
        for (int nb = 0; nb < 4; ++nb) {
            const _Float16* vp = vh + (size_t)(nb * 16 + l15) * Sc + kbase + quad * 8;
            vf0[nb] = *(const f16x8*)vp;
            vf1[nb] = *(const f16x8*)(vp + 32);
        }

        // ---- (5) issue rel(tile i+1): AFTER V so PV's wait keeps it -------
        if (i < 15) {
            const int knext = ((phase + i + 1) & 15) * 64;
#pragma unroll
            for (int g = 0; g < 4; ++g)
                rl[g] = *(const float4*)(relp + knext + g * 16);
        }
        __builtin_amdgcn_sched_barrier(0);

        // ---- (6) scale + rel (from LDS, lgkm) + mask; online softmax ------
        float rb[16];
#pragma unroll
        for (int nb = 0; nb < 4; ++nb)
#pragma unroll
            for (int rj = 0; rj < 4; ++rj)
                rb[nb * 4 + rj] = rel_lds[w][quad * 4 + rj][nb * 16 + l15];

#pragma unroll
        for (int nb = 0; nb < 4; ++nb)
#pragma unroll
            for (int rj = 0; rj < 4; ++rj)
                sc[nb][rj] = sc[nb][rj] * 0.125f + rb[nb * 4 + rj] + mk[nb];

#pragma unroll
        for (int rj = 0; rj < 4; ++rj) {
            float mx = fmaxf(fmaxf(sc[0][rj], sc[1][rj]), fmaxf(sc[2][rj], sc[3][rj]));
#pragma unroll
            for (int off = 1; off < 16; off <<= 1) mx = fmaxf(mx, __shfl_xor(mx, off));
            const float mnew  = fmaxf(m_run[rj], mx);
            const float alpha = __expf(m_run[rj] - mnew);
            float rs = 0.f;
#pragma unroll
            for (int nb = 0; nb < 4; ++nb) {
                const float p = __expf(sc[nb][rj] - mnew);
                sc[nb][rj] = p;
                rs += p;
            }
#pragma unroll
            for (int off = 1; off < 16; off <<= 1) rs += __shfl_xor(rs, off);
            m_run[rj] = mnew;
            l_run[rj] = l_run[rj] * alpha + rs;
            o[0][rj] *= alpha; o[1][rj] *= alpha; o[2][rj] *= alpha; o[3][rj] *= alpha;
        }

        // ---- (7) P: C layout -> A layout via per-wave LDS (no barriers) ---
#pragma unroll
        for (int nb = 0; nb < 4; ++nb)
#pragma unroll
            for (int rj = 0; rj < 4; ++rj)
                lds_p[w][quad * 4 + rj][nb * 16 + l15] = (_Float16)sc[nb][rj];
        f16x8 ap0 = *(const f16x8*)&lds_p[w][l15][quad * 8];
        f16x8 ap1 = *(const f16x8*)&lds_p[w][l15][32 + quad * 8];

        // ---- (8) O += P V (wait V: rel(tile i+1) stays in flight) ---------
#pragma unroll
        for (int nb = 0; nb < 4; ++nb) {
            o[nb] = MFMA16(ap0, vf0[nb], o[nb]);
            o[nb] = MFMA16(ap1, vf1[nb], o[nb]);
        }
    }

    // ---- epilogue ---------------------------------------------------------
#pragma unroll
    for (int rj = 0; rj < 4; ++rj) {
        const float linv = 1.0f / l_run[rj];
        const int qrow = q0w + quad * 4 + rj;
#pragma unroll
        for (int nb = 0; nb < 4; ++nb)
            out[((size_t)(b * Sc + qrow)) * Hc + h * HDc + nb * 16 + l15] =
                o[nb][rj] * linv;
    }
}

extern "C" void kernel_launch(void* const* d_in, const int* in_sizes, int n_in,
                              void* d_out, int out_size, void* d_ws, size_t ws_size,
                              hipStream_t stream) {
    const float* hs   = (const float*)d_in[0];
    const float* mask = (const float*)d_in[1];
    const float* rel  = (const float*)d_in[2];
    const float* Wq   = (const float*)d_in[3];
    const float* bq   = (const float*)d_in[4];
    const float* Wk   = (const float*)d_in[5];
    const float* bk   = (const float*)d_in[6];
    const float* Wv   = (const float*)d_in[7];
    const float* bv   = (const float*)d_in[8];
    float* out = (float*)d_out;

    const size_t elems = (size_t)Bc * Sc * Hc;        // 4,194,304
    _Float16* hs16 = (_Float16*)d_ws;                 // 8 MB
    _Float16* w16  = hs16 + elems;                    // 1.5 MB
    _Float16* qws  = w16 + (size_t)3 * Hc * Hc;       // 8 MB
    _Float16* kws  = qws + elems;                     // 8 MB
    _Float16* vws  = kws + elems;                     // 8 MB   (total ~33.5 MB)

    const int cvt_blocks = (int)(((size_t)Bc * Sc * Hc + 3 * Hc * Hc) / 4 / 256);
    cvt_f16<<<cvt_blocks, 256, 0, stream>>>(hs, Wq, Wk, Wv, hs16, w16);
    qkv_gemm<<<dim3(64, 12), 256, 0, stream>>>(hs16, w16, bq, bk, bv,
                                               qws, kws, vws);
    attn<<<dim3(32, 64), 128, 0, stream>>>(qws, kws, vws, rel, mask, out);
}